// Round 14
// baseline (329.059 us; speedup 1.0000x reference)
//
#include <hip/hip_runtime.h>
#include <math.h>

#define NG 256     // NUM_GRAPHS
#define NBLK 256   // blocks in histogram / pair-scatter passes
// bucket = target >> 8 (256 nodes/bucket, NB<=512); src packs in 17 bits (N <= 131072)

// fp8-e4m3 staging scales (powers of 2: exactly invertible)
#define S1F 16.0f
#define IS1F 0.0625f
#define S2F 64.0f
#define IS2F 0.015625f

typedef __attribute__((ext_vector_type(2))) float f32x2;

__device__ __forceinline__ unsigned enc4(float f0, float f1, float f2, float f3) {
    int r = __builtin_amdgcn_cvt_pk_fp8_f32(f0, f1, 0, false);
    r = __builtin_amdgcn_cvt_pk_fp8_f32(f2, f3, r, true);
    return (unsigned)r;
}
__device__ __forceinline__ void acc8(uint2 v, float (&a)[8]) {
    f32x2 p0 = __builtin_amdgcn_cvt_pk_f32_fp8((int)v.x, false);
    f32x2 p1 = __builtin_amdgcn_cvt_pk_f32_fp8((int)v.x, true);
    f32x2 p2 = __builtin_amdgcn_cvt_pk_f32_fp8((int)v.y, false);
    f32x2 p3 = __builtin_amdgcn_cvt_pk_f32_fp8((int)v.y, true);
    a[0] += p0[0]; a[1] += p0[1]; a[2] += p1[0]; a[3] += p1[1];
    a[4] += p2[0]; a[5] += p2[1]; a[6] += p3[0]; a[7] += p3[1];
}

// ---------------------------------------------------------------------------
// K1: per-block histogram of edge targets into NB buckets (LDS atomics), then
// reserve this block's range in each bucket via one global atomic per bucket.
__global__ __launch_bounds__(256) void hist_bucket_kernel(
        const int* __restrict__ col, int* __restrict__ blockOff,
        int* __restrict__ bucketTot, int E, int NB) {
    __shared__ int h[512];
    h[threadIdx.x] = 0; h[threadIdx.x + 256] = 0;
    __syncthreads();
    const int chunk = (((E + NBLK - 1) / NBLK) + 3) & ~3;   // 4-aligned per-block chunk
    const int beg = blockIdx.x * chunk;
    const int end = min(beg + chunk, E);
    if ((E & 3) == 0) {
        int e = beg + threadIdx.x * 4;
        for (; e + 3 < end; e += 1024) {
            int4 c = *(const int4*)(col + e);
            atomicAdd(&h[c.x >> 8], 1);
            atomicAdd(&h[c.y >> 8], 1);
            atomicAdd(&h[c.z >> 8], 1);
            atomicAdd(&h[c.w >> 8], 1);
        }
        for (; e < end; e++) atomicAdd(&h[col[e] >> 8], 1);
    } else {
        for (int e = beg + threadIdx.x; e < end; e += 256)
            atomicAdd(&h[col[e] >> 8], 1);
    }
    __syncthreads();
    for (int t = threadIdx.x; t < NB; t += 256) {
        int off = atomicAdd(&bucketTot[t], h[t]);   // reserve range (order arbitrary)
        blockOff[t * NBLK + blockIdx.x] = off;
    }
}

// K2: tiny exclusive scan over bucketTot[NB] -> bucketBase[NB+1]  (NB <= 512)
__global__ __launch_bounds__(512) void tiny_scan_kernel(
        const int* __restrict__ bucketTot, int* __restrict__ bucketBase, int NB) {
    __shared__ int part[512];
    const int t = threadIdx.x;
    int v = (t < NB) ? bucketTot[t] : 0;
    part[t] = v;
    __syncthreads();
    for (int o = 1; o < 512; o <<= 1) {
        int u = (t >= o) ? part[t - o] : 0;
        __syncthreads();
        part[t] += u;
        __syncthreads();
    }
    if (t < NB) bucketBase[t] = part[t] - v;   // exclusive
    if (t == NB) bucketBase[NB] = part[NB - 1];
    if (t == 511 && NB == 512) bucketBase[NB] = part[511];
}

// K3: scatter packed (local_tgt<<17 | src) pairs, grouped by bucket (LDS cursors)
__global__ __launch_bounds__(256) void scatter_pairs_kernel(
        const int* __restrict__ ei, const int* __restrict__ blockOff,
        const int* __restrict__ bucketBase, int* __restrict__ pairs, int E, int NB) {
    __shared__ int cur[512];
    for (int t = threadIdx.x; t < NB; t += 256)
        cur[t] = bucketBase[t] + blockOff[t * NBLK + blockIdx.x];
    __syncthreads();
    const int chunk = (((E + NBLK - 1) / NBLK) + 3) & ~3;
    const int beg = blockIdx.x * chunk;
    const int end = min(beg + chunk, E);
    if ((E & 3) == 0) {
        int e = beg + threadIdx.x * 4;
        for (; e + 3 < end; e += 1024) {
            int4 s = *(const int4*)(ei + e);
            int4 tg = *(const int4*)(ei + E + e);
            int p0 = atomicAdd(&cur[tg.x >> 8], 1);
            pairs[p0] = (int)(((unsigned)(tg.x & 255) << 17) | (unsigned)s.x);
            int p1 = atomicAdd(&cur[tg.y >> 8], 1);
            pairs[p1] = (int)(((unsigned)(tg.y & 255) << 17) | (unsigned)s.y);
            int p2 = atomicAdd(&cur[tg.z >> 8], 1);
            pairs[p2] = (int)(((unsigned)(tg.z & 255) << 17) | (unsigned)s.z);
            int p3 = atomicAdd(&cur[tg.w >> 8], 1);
            pairs[p3] = (int)(((unsigned)(tg.w & 255) << 17) | (unsigned)s.w);
        }
        for (; e < end; e++) {
            int src = ei[e];
            int tgt = ei[E + e];
            int pos = atomicAdd(&cur[tgt >> 8], 1);
            pairs[pos] = (int)(((unsigned)(tgt & 255) << 17) | (unsigned)src);
        }
    } else {
        for (int e = beg + threadIdx.x; e < end; e += 256) {
            int src = ei[e];
            int tgt = ei[E + e];
            int pos = atomicAdd(&cur[tgt >> 8], 1);
            pairs[pos] = (int)(((unsigned)(tgt & 255) << 17) | (unsigned)src);
        }
    }
}

// K4: one block per bucket (256 nodes): LDS hist + scan -> rowptr, dinv, adj
__global__ __launch_bounds__(256) void csr_bucket_kernel(
        const int* __restrict__ pairs, const int* __restrict__ bucketBase,
        int* __restrict__ rowptr, int* __restrict__ adj,
        float* __restrict__ dinv, int N, int E) {
    __shared__ int h[256];
    __shared__ int sc[256];
    __shared__ int cur[256];
    const int b = blockIdx.x, t = threadIdx.x;
    const int base = bucketBase[b];
    const int end = bucketBase[b + 1];
    h[t] = 0;
    __syncthreads();
    for (int i = base + t; i < end; i += 256)
        atomicAdd(&h[(unsigned)pairs[i] >> 17], 1);
    __syncthreads();
    const int v = h[t];
    sc[t] = v;
    __syncthreads();
    for (int o = 1; o < 256; o <<= 1) {
        int u = (t >= o) ? sc[t - o] : 0;
        __syncthreads();
        sc[t] += u;
        __syncthreads();
    }
    const int ex = sc[t] - v;
    const int node = (b << 8) + t;
    if (node < N) {
        rowptr[node] = base + ex;
        dinv[node] = rsqrtf((float)v + 1.0f);
    }
    cur[t] = base + ex;
    __syncthreads();
    for (int i = base + t; i < end; i += 256) {
        unsigned p = (unsigned)pairs[i];
        int pos = atomicAdd(&cur[p >> 17], 1);
        adj[pos] = (int)(p & 0x1FFFFu);
    }
    if (b == 0 && t == 0) rowptr[N] = E;
}

// K5: segment bounds from sorted batch: starts[g] = lower_bound(batch, g), starts[NG]=N
__global__ __launch_bounds__(256) void bounds_kernel(
        const int* __restrict__ batch, int* __restrict__ starts, int N) {
    int i = blockIdx.x * blockDim.x + threadIdx.x;
    if (i >= N) return;
    int b = batch[i];
    int bp = (i == 0) ? -1 : batch[i - 1];
    for (int g = bp + 1; g <= b; g++) starts[g] = i;
    if (i == N - 1)
        for (int g = b + 1; g <= NG; g++) starts[g] = N;
}

// ---------------------------------------------------------------------------
// hs1[i][f] = fp8( (x[i]@W1)[f] * dinv[i] * S1 )   (32 feats -> 32 B rows)
__global__ __launch_bounds__(256) void hs1_kernel(
        const float* __restrict__ x, const float* __restrict__ W,
        const float* __restrict__ dinv, unsigned* __restrict__ hs, int N) {
    __shared__ float Ws[32 * 32];
    __shared__ float tmp[8][32];
    for (int t = threadIdx.x; t < 1024; t += blockDim.x) Ws[t] = W[t];
    __syncthreads();
    const int tid = threadIdx.x;
    const int node = blockIdx.x * 8 + (tid >> 5);
    const int n = tid >> 5, f = tid & 31;
    if (node < N) {
        const float* xr = x + (size_t)node * 32;
        float acc = 0.f;
#pragma unroll
        for (int k = 0; k < 32; k++) acc += xr[k] * Ws[k * 32 + f];
        tmp[n][f] = acc * dinv[node] * S1F;
        if (f < 8)   // same-wave producer/consumer
            hs[(size_t)node * 8 + f] = enc4(tmp[n][4 * f], tmp[n][4 * f + 1],
                                            tmp[n][4 * f + 2], tmp[n][4 * f + 3]);
    }
}

// gather layer 1 (fp8 rows, 32 B: 4 lanes/row, 8 edge slots, 32 edges/iter
// with 4 independent row loads in flight)
__global__ __launch_bounds__(256) void gather1_kernel(
        const int* __restrict__ rowptr, const int* __restrict__ adj,
        const uint2* __restrict__ hs1q, const float* __restrict__ dinv,
        const float* __restrict__ b1, const float* __restrict__ W2,
        unsigned* __restrict__ hs2out, int N) {
    __shared__ float W2s[32 * 24];
    __shared__ float b1s[32];
    __shared__ float h1row[8][32];
    __shared__ float hs2t[8][32];
    const int tid = threadIdx.x;
    for (int t = tid; t < 768; t += 256) W2s[t] = W2[t];
    if (tid < 32) b1s[tid] = b1[tid];

    const int node = blockIdx.x * 8 + (tid >> 5);
    const int n = tid >> 5;
    const int l = tid & 31;
    const int f8 = l & 3;        // feature octet
    const int e8 = l >> 2;       // edge slot 0..7
    const bool valid = node < N;

    int beg = 0, cnt = 0;
    if (valid) { beg = rowptr[node]; cnt = rowptr[node + 1] - beg; }
    const int* ap = adj + beg;
    float a[8] = {0.f, 0.f, 0.f, 0.f, 0.f, 0.f, 0.f, 0.f};
    int j = 0;
    for (; j + 32 <= cnt; j += 32) {            // 32 edges/iter, 4 loads in flight
        int s0 = ap[j + e8];
        int s1 = ap[j + 8 + e8];
        int s2 = ap[j + 16 + e8];
        int s3 = ap[j + 24 + e8];
        uint2 v0 = hs1q[(size_t)s0 * 4 + f8];
        uint2 v1 = hs1q[(size_t)s1 * 4 + f8];
        uint2 v2 = hs1q[(size_t)s2 * 4 + f8];
        uint2 v3 = hs1q[(size_t)s3 * 4 + f8];
        acc8(v0, a); acc8(v1, a); acc8(v2, a); acc8(v3, a);
    }
    for (; j + 16 <= cnt; j += 16) {
        int s0 = ap[j + e8];
        int s1 = ap[j + 8 + e8];
        uint2 v0 = hs1q[(size_t)s0 * 4 + f8];
        uint2 v1 = hs1q[(size_t)s1 * 4 + f8];
        acc8(v0, a); acc8(v1, a);
    }
    for (; j + 8 <= cnt; j += 8) {
        int s0 = ap[j + e8];
        acc8(hs1q[(size_t)s0 * 4 + f8], a);
    }
    if (e8 < cnt - j) {                          // tail 0..7 edges
        int s0 = ap[j + e8];
        acc8(hs1q[(size_t)s0 * 4 + f8], a);
    }
#pragma unroll
    for (int k = 0; k < 8; k++) {                // fold 8 edge slots (lane bits 2,3,4)
        a[k] += __shfl_xor(a[k], 4);
        a[k] += __shfl_xor(a[k], 8);
        a[k] += __shfl_xor(a[k], 16);
    }

    __syncthreads();   // weight/bias staging visibility (all threads reach here)

    float di = 0.f;
    if (valid) {
        di = dinv[node];
        if (e8 == 0) {                           // lanes l<4 finalize 8 feats each
            float sv[8] = {0.f, 0.f, 0.f, 0.f, 0.f, 0.f, 0.f, 0.f};
            acc8(hs1q[(size_t)node * 4 + f8], sv);   // self-loop term
            const float c = di * IS1F;
#pragma unroll
            for (int k = 0; k < 8; k++)
                h1row[n][8 * f8 + k] = fmaxf(c * (a[k] + sv[k]) + b1s[8 * f8 + k], 0.f);
        }
    }
    // same-wave producer/consumer through LDS: no barrier needed
    if (valid) {
        float aa = 0.f;
        if (l < 24) {
#pragma unroll
            for (int k = 0; k < 32; k++) aa += h1row[n][k] * W2s[k * 24 + l];
        }
        hs2t[n][l] = (l < 24) ? aa * di * S2F : 0.f;
        if (l < 8)
            hs2out[(size_t)node * 8 + l] = enc4(hs2t[n][4 * l], hs2t[n][4 * l + 1],
                                                hs2t[n][4 * l + 2], hs2t[n][4 * l + 3]);
    }
}

// gather layer 2 (fp8 rows, 32 B, deep unroll) + fused finalize + node-MLP
__global__ __launch_bounds__(256) void gather2_kernel(
        const int* __restrict__ rowptr, const int* __restrict__ adj,
        const uint2* __restrict__ hs2q, const float* __restrict__ dinv,
        const float* __restrict__ b2,
        const float* __restrict__ Wn1, const float* __restrict__ bn1,
        const float* __restrict__ Wn2, const float* __restrict__ bn2,
        float* __restrict__ h2out, float* __restrict__ vout, int N) {
    __shared__ float Wn1s[24 * 16];
    __shared__ float b2s[32], bn1s[16], Wn2s[16];
    __shared__ float h2row[8][32];
    const int tid = threadIdx.x;
    for (int t = tid; t < 384; t += 256) Wn1s[t] = Wn1[t];
    if (tid < 32) b2s[tid] = (tid < 24) ? b2[tid] : 0.f;
    if (tid < 16) { bn1s[tid] = bn1[tid]; Wn2s[tid] = Wn2[tid]; }

    const int node = blockIdx.x * 8 + (tid >> 5);
    const int n = tid >> 5;
    const int l = tid & 31;
    const int f8 = l & 3;
    const int e8 = l >> 2;
    const bool valid = node < N;

    int beg = 0, cnt = 0;
    if (valid) { beg = rowptr[node]; cnt = rowptr[node + 1] - beg; }
    const int* ap = adj + beg;
    float a[8] = {0.f, 0.f, 0.f, 0.f, 0.f, 0.f, 0.f, 0.f};
    int j = 0;
    for (; j + 32 <= cnt; j += 32) {
        int s0 = ap[j + e8];
        int s1 = ap[j + 8 + e8];
        int s2 = ap[j + 16 + e8];
        int s3 = ap[j + 24 + e8];
        uint2 v0 = hs2q[(size_t)s0 * 4 + f8];
        uint2 v1 = hs2q[(size_t)s1 * 4 + f8];
        uint2 v2 = hs2q[(size_t)s2 * 4 + f8];
        uint2 v3 = hs2q[(size_t)s3 * 4 + f8];
        acc8(v0, a); acc8(v1, a); acc8(v2, a); acc8(v3, a);
    }
    for (; j + 16 <= cnt; j += 16) {
        int s0 = ap[j + e8];
        int s1 = ap[j + 8 + e8];
        uint2 v0 = hs2q[(size_t)s0 * 4 + f8];
        uint2 v1 = hs2q[(size_t)s1 * 4 + f8];
        acc8(v0, a); acc8(v1, a);
    }
    for (; j + 8 <= cnt; j += 8) {
        int s0 = ap[j + e8];
        acc8(hs2q[(size_t)s0 * 4 + f8], a);
    }
    if (e8 < cnt - j) {
        int s0 = ap[j + e8];
        acc8(hs2q[(size_t)s0 * 4 + f8], a);
    }
#pragma unroll
    for (int k = 0; k < 8; k++) {
        a[k] += __shfl_xor(a[k], 4);
        a[k] += __shfl_xor(a[k], 8);
        a[k] += __shfl_xor(a[k], 16);
    }

    __syncthreads();   // weight/bias staging visibility

    if (valid && e8 == 0) {
        float di = dinv[node];
        float sv[8] = {0.f, 0.f, 0.f, 0.f, 0.f, 0.f, 0.f, 0.f};
        acc8(hs2q[(size_t)node * 4 + f8], sv);
        const float c = di * IS2F;
#pragma unroll
        for (int k = 0; k < 8; k++)   // pad feats (>=24): staged 0, b2s 0 -> h2 0
            h2row[n][8 * f8 + k] = fmaxf(c * (a[k] + sv[k]) + b2s[8 * f8 + k], 0.f);
    }
    // same-wave producer/consumer through LDS
    if (valid && l < 24) h2out[(size_t)node * 24 + l] = h2row[n][l];

    float val = 0.f;
    if (valid && l < 16) {
        float u = bn1s[l];
#pragma unroll
        for (int k = 0; k < 24; k++) u += h2row[n][k] * Wn1s[k * 16 + l];
        val = fmaxf(u, 0.f) * Wn2s[l];
    }
    val += __shfl_down(val, 8, 16);
    val += __shfl_down(val, 4, 16);
    val += __shfl_down(val, 2, 16);
    val += __shfl_down(val, 1, 16);
    if (valid && l == 0) vout[node] = val + bn2[0];
}

// ---------------------------------------------------------------------------
// One block per graph (precomputed bounds): feature-parallel segment reduction.
// thread = (wave w, half) -> node slot 0..7 ; lane&31 -> feature.
__global__ __launch_bounds__(256) void graph_kernel(
        const float* __restrict__ v, const float* __restrict__ h2,
        const int* __restrict__ starts,
        const float* __restrict__ Wg, const float* __restrict__ bg,
        const float* __restrict__ Wt, const float* __restrict__ bt,
        const float* __restrict__ Wb1p, const float* __restrict__ bb1p,
        const float* __restrict__ Wb2p, const float* __restrict__ bb2p,
        float* __restrict__ out_t, float* __restrict__ out_n,
        float* __restrict__ bbpre, int N) {
    const int g = blockIdx.x;
    const int tid = threadIdx.x;
    const int lane = tid & 63;
    const int wv = tid >> 6;

    const int start = starts[g];
    const int end = starts[g + 1];

    __shared__ float sm[4];
    __shared__ float pH[4][24], pW[4][24], pS[4];

    // pass A: max of v over the segment (grid-stride, wave reduce)
    float m = -INFINITY;
    for (int idx = start + tid; idx < end; idx += 256) m = fmaxf(m, v[idx]);
#pragma unroll
    for (int off = 32; off > 0; off >>= 1) m = fmaxf(m, __shfl_down(m, off, 64));
    if (lane == 0) sm[wv] = m;
    __syncthreads();
    m = fmaxf(fmaxf(sm[0], sm[1]), fmaxf(sm[2], sm[3]));

    // pass B: feature-parallel accumulation; 8 node slots x 32 feats
    const int half = lane >> 5;
    const int slot = wv * 2 + half;       // 0..7
    const int feat = lane & 31;
    float hs = 0.f, ws = 0.f, se = 0.f;
    for (int base_i = start + slot; base_i < end; base_i += 8) {
        float vv = v[base_i];             // broadcast within 32-lane group
        float e = __expf(vv - m);
        if (feat == 0) se += e;
        if (feat < 24) {
            float hv = h2[(size_t)base_i * 24 + feat];
            hs += hv;
            ws += e * hv;
        }
    }
    // fold the two slots within this wave (lanes differ by 32)
    hs += __shfl_xor(hs, 32, 64);
    ws += __shfl_xor(ws, 32, 64);
    se += __shfl_xor(se, 32, 64);
    if (lane < 24) { pH[wv][lane] = hs; pW[wv][lane] = ws; }
    if (lane == 0) pS[wv] = se;
    __syncthreads();
    const float stot = pS[0] + pS[1] + pS[2] + pS[3];
    const float invs = (stot > 0.f) ? 1.f / stot : 0.f;

    // pass C: write normalized per-node softmax
    for (int idx = start + tid; idx < end; idx += 256)
        out_n[idx] = __expf(v[idx] - m) * invs;

    // graph-level heads on thread 0 (tiny)
    if (tid == 0) {
        float hsumT[24], wsumT[24];
#pragma unroll
        for (int f = 0; f < 24; f++) {
            hsumT[f] = pH[0][f] + pH[1][f] + pH[2][f] + pH[3][f];
            wsumT[f] = pW[0][f] + pW[1][f] + pW[2][f] + pW[3][f];
        }
        float cnt = (float)(end - start);
        float denom = fmaxf(cnt, 1.0f);

        float mean[24];
#pragma unroll
        for (int f = 0; f < 24; f++) mean[f] = hsumT[f] / denom;
        float gout[32];
        for (int o = 0; o < 32; o++) {
            float a = bg[o];
#pragma unroll
            for (int k = 0; k < 24; k++) a += mean[k] * Wg[k * 32 + o];
            gout[o] = a;
        }
        float t0 = bt[0], t1 = bt[1];
#pragma unroll
        for (int k = 0; k < 32; k++) { t0 += gout[k] * Wt[k * 2]; t1 += gout[k] * Wt[k * 2 + 1]; }
        float tm = fmaxf(t0, t1);
        float e0 = __expf(t0 - tm), e1 = __expf(t1 - tm);
        float ts = e0 + e1;
        out_t[g * 2 + 0] = e0 / ts;
        out_t[g * 2 + 1] = e1 / ts;

        float bf[24];
#pragma unroll
        for (int f = 0; f < 24; f++) bf[f] = wsumT[f] * invs;
        float u[16];
        for (int j = 0; j < 16; j++) {
            float a = bb1p[j];
#pragma unroll
            for (int k = 0; k < 24; k++) a += bf[k] * Wb1p[k * 16 + j];
            u[j] = fmaxf(a, 0.f);
        }
        for (int c = 0; c < 3; c++) {
            float a = bb2p[c];
#pragma unroll
            for (int j = 0; j < 16; j++) a += u[j] * Wb2p[j * 3 + c];
            bbpre[g * 3 + c] = a;
        }
    }
}

// column softmax over the 256 graphs (axis=0), 3 columns
__global__ __launch_bounds__(256) void bb_kernel(
        const float* __restrict__ bbpre, float* __restrict__ out_bb) {
    __shared__ float red[NG];
    int g = threadIdx.x;
#pragma unroll
    for (int c = 0; c < 3; c++) {
        float vv = bbpre[g * 3 + c];
        red[g] = vv;
        __syncthreads();
        for (int off = 128; off > 0; off >>= 1) {
            if (g < off) red[g] = fmaxf(red[g], red[g + off]);
            __syncthreads();
        }
        float m = red[0];
        __syncthreads();
        float e = __expf(vv - m);
        red[g] = e;
        __syncthreads();
        for (int off = 128; off > 0; off >>= 1) {
            if (g < off) red[g] += red[g + off];
            __syncthreads();
        }
        float ssum = red[0];
        __syncthreads();
        out_bb[g * 3 + c] = e / ssum;
    }
}

extern "C" void kernel_launch(void* const* d_in, const int* in_sizes, int n_in,
                              void* d_out, int out_size, void* d_ws, size_t ws_size,
                              hipStream_t stream) {
    const float* x   = (const float*)d_in[0];
    const int*   ei  = (const int*)d_in[1];    // [2,E] flat: row=ei[0..E), col=ei[E..2E)
    const int*   bat = (const int*)d_in[2];
    const float* W1  = (const float*)d_in[3];
    const float* b1  = (const float*)d_in[4];
    const float* W2  = (const float*)d_in[5];
    const float* b2  = (const float*)d_in[6];
    const float* Wg  = (const float*)d_in[7];
    const float* bg  = (const float*)d_in[8];
    const float* Wt  = (const float*)d_in[9];
    const float* bt  = (const float*)d_in[10];
    const float* Wn1 = (const float*)d_in[11];
    const float* bn1 = (const float*)d_in[12];
    const float* Wn2 = (const float*)d_in[13];
    const float* bn2 = (const float*)d_in[14];
    const float* Wb1 = (const float*)d_in[15];
    const float* bb1 = (const float*)d_in[16];
    const float* Wb2 = (const float*)d_in[17];
    const float* bb2 = (const float*)d_in[18];

    const int N = in_sizes[2];
    const int E = in_sizes[1] / 2;
    const int NB = (N + 255) >> 8;       // buckets of 256 nodes
    const int M = NB * NBLK;             // blockOff matrix size

    // workspace layout (4B units):
    // persistent: rowptr[N+1] | dinv[N] | adj[E] | bucketBase[NB+1] | bucketTot[NB] | starts[NG+1]
    // transient (aliased union):
    //   build:   blockOff[M] | pairs[E]
    //   compute: hs1 fp8 (2N) -> h2 f32 (24N) + v (N) ; hs2 fp8 at +26N (2N) ; bbpre at +28N
    auto rnd4 = [](size_t v) { return (v + 3) & ~(size_t)3; };
    size_t oRow = 0;
    size_t oDin = oRow + rnd4((size_t)N + 1);
    size_t oAdj = oDin + rnd4((size_t)N);
    size_t oBB  = oAdj + rnd4((size_t)E);
    size_t oTot = oBB + rnd4((size_t)NB + 1);
    size_t oSt  = oTot + rnd4((size_t)NB);
    size_t oT   = oSt + rnd4((size_t)NG + 1);
    size_t oPar = oT + rnd4((size_t)M);

    int*   wsi     = (int*)d_ws;
    float* wsf     = (float*)d_ws;
    int*   rowptr  = wsi + oRow;
    float* dinv    = wsf + oDin;
    int*   adj     = wsi + oAdj;
    int*   bbase   = wsi + oBB;
    int*   btot    = wsi + oTot;
    int*   starts  = wsi + oSt;
    int*   blkoff  = wsi + oT;
    int*   pairs   = wsi + oPar;
    unsigned* hs1b = (unsigned*)(wsf + oT);                  // 2N units
    float* h2      = wsf + oT;                               // reuses hs1b region after gather1
    float* vbuf    = wsf + oT + (size_t)24 * N;
    unsigned* hs2b = (unsigned*)(wsf + oT + (size_t)26 * N); // 2N units
    float* bbpre   = wsf + oT + (size_t)28 * N;

    float* out_t  = (float*)d_out;          // [256,2]
    float* out_n  = out_t + 2 * NG;         // [N,1]
    float* out_bb = out_t + 2 * NG + N;     // [256,3]

    const int B = 256;

    // CSR build + segment bounds
    (void)hipMemsetAsync(btot, 0, (size_t)NB * sizeof(int), stream);
    bounds_kernel<<<(N + B - 1) / B, B, 0, stream>>>(bat, starts, N);
    hist_bucket_kernel<<<NBLK, B, 0, stream>>>(ei + E, blkoff, btot, E, NB);
    tiny_scan_kernel<<<1, 512, 0, stream>>>(btot, bbase, NB);
    scatter_pairs_kernel<<<NBLK, B, 0, stream>>>(ei, blkoff, bbase, pairs, E, NB);
    csr_bucket_kernel<<<NB, B, 0, stream>>>(pairs, bbase, rowptr, adj, dinv, N, E);

    // GCN + heads (fp8 staging rows, fp32 accumulation, 4-deep gather unroll)
    hs1_kernel<<<(N + 7) / 8, B, 0, stream>>>(x, W1, dinv, hs1b, N);
    gather1_kernel<<<(N + 7) / 8, B, 0, stream>>>(rowptr, adj, (const uint2*)hs1b,
                                                  dinv, b1, W2, hs2b, N);
    gather2_kernel<<<(N + 7) / 8, B, 0, stream>>>(rowptr, adj, (const uint2*)hs2b,
                                                  dinv, b2, Wn1, bn1, Wn2, bn2, h2, vbuf, N);
    graph_kernel<<<NG, B, 0, stream>>>(vbuf, h2, starts, Wg, bg, Wt, bt,
                                       Wb1, bb1, Wb2, bb2, out_t, out_n, bbpre, N);
    bb_kernel<<<1, B, 0, stream>>>(bbpre, out_bb);
}

// Round 15
// 297.210 us; speedup vs baseline: 1.1072x; 1.1072x over previous
//
#include <hip/hip_runtime.h>
#include <math.h>

#define NG 256     // NUM_GRAPHS
#define NBLK 256   // blocks in histogram / pair-scatter passes
// bucket = target >> 8 (256 nodes/bucket, NB<=512); src packs in 17 bits (N <= 131072)

// fp8-e4m3 staging scales (powers of 2: exactly invertible)
#define S1F 16.0f
#define IS1F 0.0625f
#define S2F 64.0f
#define IS2F 0.015625f

typedef __attribute__((ext_vector_type(2))) float f32x2;

__device__ __forceinline__ unsigned enc4(float f0, float f1, float f2, float f3) {
    int r = __builtin_amdgcn_cvt_pk_fp8_f32(f0, f1, 0, false);
    r = __builtin_amdgcn_cvt_pk_fp8_f32(f2, f3, r, true);
    return (unsigned)r;
}
__device__ __forceinline__ void acc8(uint2 v, float (&a)[8]) {
    f32x2 p0 = __builtin_amdgcn_cvt_pk_f32_fp8((int)v.x, false);
    f32x2 p1 = __builtin_amdgcn_cvt_pk_f32_fp8((int)v.x, true);
    f32x2 p2 = __builtin_amdgcn_cvt_pk_f32_fp8((int)v.y, false);
    f32x2 p3 = __builtin_amdgcn_cvt_pk_f32_fp8((int)v.y, true);
    a[0] += p0[0]; a[1] += p0[1]; a[2] += p1[0]; a[3] += p1[1];
    a[4] += p2[0]; a[5] += p2[1]; a[6] += p3[0]; a[7] += p3[1];
}

// ---------------------------------------------------------------------------
// K1: per-block histogram of edge targets into NB buckets (LDS atomics), then
// reserve this block's range in each bucket via one global atomic per bucket.
__global__ __launch_bounds__(256) void hist_bucket_kernel(
        const int* __restrict__ col, int* __restrict__ blockOff,
        int* __restrict__ bucketTot, int E, int NB) {
    __shared__ int h[512];
    h[threadIdx.x] = 0; h[threadIdx.x + 256] = 0;
    __syncthreads();
    const int chunk = (((E + NBLK - 1) / NBLK) + 3) & ~3;   // 4-aligned per-block chunk
    const int beg = blockIdx.x * chunk;
    const int end = min(beg + chunk, E);
    if ((E & 3) == 0) {
        int e = beg + threadIdx.x * 4;
        for (; e + 3 < end; e += 1024) {
            int4 c = *(const int4*)(col + e);
            atomicAdd(&h[c.x >> 8], 1);
            atomicAdd(&h[c.y >> 8], 1);
            atomicAdd(&h[c.z >> 8], 1);
            atomicAdd(&h[c.w >> 8], 1);
        }
        for (; e < end; e++) atomicAdd(&h[col[e] >> 8], 1);
    } else {
        for (int e = beg + threadIdx.x; e < end; e += 256)
            atomicAdd(&h[col[e] >> 8], 1);
    }
    __syncthreads();
    for (int t = threadIdx.x; t < NB; t += 256) {
        int off = atomicAdd(&bucketTot[t], h[t]);   // reserve range (order arbitrary)
        blockOff[t * NBLK + blockIdx.x] = off;
    }
}

// K2: tiny exclusive scan over bucketTot[NB] -> bucketBase[NB+1]  (NB <= 512)
__global__ __launch_bounds__(512) void tiny_scan_kernel(
        const int* __restrict__ bucketTot, int* __restrict__ bucketBase, int NB) {
    __shared__ int part[512];
    const int t = threadIdx.x;
    int v = (t < NB) ? bucketTot[t] : 0;
    part[t] = v;
    __syncthreads();
    for (int o = 1; o < 512; o <<= 1) {
        int u = (t >= o) ? part[t - o] : 0;
        __syncthreads();
        part[t] += u;
        __syncthreads();
    }
    if (t < NB) bucketBase[t] = part[t] - v;   // exclusive
    if (t == NB) bucketBase[NB] = part[NB - 1];
    if (t == 511 && NB == 512) bucketBase[NB] = part[511];
}

// K3: scatter packed (local_tgt<<17 | src) pairs, grouped by bucket (LDS cursors)
__global__ __launch_bounds__(256) void scatter_pairs_kernel(
        const int* __restrict__ ei, const int* __restrict__ blockOff,
        const int* __restrict__ bucketBase, int* __restrict__ pairs, int E, int NB) {
    __shared__ int cur[512];
    for (int t = threadIdx.x; t < NB; t += 256)
        cur[t] = bucketBase[t] + blockOff[t * NBLK + blockIdx.x];
    __syncthreads();
    const int chunk = (((E + NBLK - 1) / NBLK) + 3) & ~3;
    const int beg = blockIdx.x * chunk;
    const int end = min(beg + chunk, E);
    if ((E & 3) == 0) {
        int e = beg + threadIdx.x * 4;
        for (; e + 3 < end; e += 1024) {
            int4 s = *(const int4*)(ei + e);
            int4 tg = *(const int4*)(ei + E + e);
            int p0 = atomicAdd(&cur[tg.x >> 8], 1);
            pairs[p0] = (int)(((unsigned)(tg.x & 255) << 17) | (unsigned)s.x);
            int p1 = atomicAdd(&cur[tg.y >> 8], 1);
            pairs[p1] = (int)(((unsigned)(tg.y & 255) << 17) | (unsigned)s.y);
            int p2 = atomicAdd(&cur[tg.z >> 8], 1);
            pairs[p2] = (int)(((unsigned)(tg.z & 255) << 17) | (unsigned)s.z);
            int p3 = atomicAdd(&cur[tg.w >> 8], 1);
            pairs[p3] = (int)(((unsigned)(tg.w & 255) << 17) | (unsigned)s.w);
        }
        for (; e < end; e++) {
            int src = ei[e];
            int tgt = ei[E + e];
            int pos = atomicAdd(&cur[tgt >> 8], 1);
            pairs[pos] = (int)(((unsigned)(tgt & 255) << 17) | (unsigned)src);
        }
    } else {
        for (int e = beg + threadIdx.x; e < end; e += 256) {
            int src = ei[e];
            int tgt = ei[E + e];
            int pos = atomicAdd(&cur[tgt >> 8], 1);
            pairs[pos] = (int)(((unsigned)(tgt & 255) << 17) | (unsigned)src);
        }
    }
}

// K4: one block per bucket (256 nodes): LDS hist + scan -> rowptr, dinv, adj
__global__ __launch_bounds__(256) void csr_bucket_kernel(
        const int* __restrict__ pairs, const int* __restrict__ bucketBase,
        int* __restrict__ rowptr, int* __restrict__ adj,
        float* __restrict__ dinv, int N, int E) {
    __shared__ int h[256];
    __shared__ int sc[256];
    __shared__ int cur[256];
    const int b = blockIdx.x, t = threadIdx.x;
    const int base = bucketBase[b];
    const int end = bucketBase[b + 1];
    h[t] = 0;
    __syncthreads();
    for (int i = base + t; i < end; i += 256)
        atomicAdd(&h[(unsigned)pairs[i] >> 17], 1);
    __syncthreads();
    const int v = h[t];
    sc[t] = v;
    __syncthreads();
    for (int o = 1; o < 256; o <<= 1) {
        int u = (t >= o) ? sc[t - o] : 0;
        __syncthreads();
        sc[t] += u;
        __syncthreads();
    }
    const int ex = sc[t] - v;
    const int node = (b << 8) + t;
    if (node < N) {
        rowptr[node] = base + ex;
        dinv[node] = rsqrtf((float)v + 1.0f);
    }
    cur[t] = base + ex;
    __syncthreads();
    for (int i = base + t; i < end; i += 256) {
        unsigned p = (unsigned)pairs[i];
        int pos = atomicAdd(&cur[p >> 17], 1);
        adj[pos] = (int)(p & 0x1FFFFu);
    }
    if (b == 0 && t == 0) rowptr[N] = E;
}

// K5: segment bounds from sorted batch: starts[g] = lower_bound(batch, g), starts[NG]=N
__global__ __launch_bounds__(256) void bounds_kernel(
        const int* __restrict__ batch, int* __restrict__ starts, int N) {
    int i = blockIdx.x * blockDim.x + threadIdx.x;
    if (i >= N) return;
    int b = batch[i];
    int bp = (i == 0) ? -1 : batch[i - 1];
    for (int g = bp + 1; g <= b; g++) starts[g] = i;
    if (i == N - 1)
        for (int g = b + 1; g <= NG; g++) starts[g] = N;
}

// ---------------------------------------------------------------------------
// hs1[i][f] = fp8( (x[i]@W1)[f] * dinv[i] * S1 )   (32 feats -> 32 B rows)
__global__ __launch_bounds__(256) void hs1_kernel(
        const float* __restrict__ x, const float* __restrict__ W,
        const float* __restrict__ dinv, unsigned* __restrict__ hs, int N) {
    __shared__ float Ws[32 * 32];
    __shared__ float tmp[8][32];
    for (int t = threadIdx.x; t < 1024; t += blockDim.x) Ws[t] = W[t];
    __syncthreads();
    const int tid = threadIdx.x;
    const int node = blockIdx.x * 8 + (tid >> 5);
    const int n = tid >> 5, f = tid & 31;
    if (node < N) {
        const float* xr = x + (size_t)node * 32;
        float acc = 0.f;
#pragma unroll
        for (int k = 0; k < 32; k++) acc += xr[k] * Ws[k * 32 + f];
        tmp[n][f] = acc * dinv[node] * S1F;
        if (f < 8)   // same-wave producer/consumer
            hs[(size_t)node * 8 + f] = enc4(tmp[n][4 * f], tmp[n][4 * f + 1],
                                            tmp[n][4 * f + 2], tmp[n][4 * f + 3]);
    }
}

// gather layer 1 (fp8 rows, 32 B: 4 lanes/row, 8 edge slots, 32 edges/iter
// with 4 independent row loads in flight)
__global__ __launch_bounds__(256) void gather1_kernel(
        const int* __restrict__ rowptr, const int* __restrict__ adj,
        const uint2* __restrict__ hs1q, const float* __restrict__ dinv,
        const float* __restrict__ b1, const float* __restrict__ W2,
        unsigned* __restrict__ hs2out, int N) {
    __shared__ float W2s[32 * 24];
    __shared__ float b1s[32];
    __shared__ float h1row[8][32];
    __shared__ float hs2t[8][32];
    const int tid = threadIdx.x;
    for (int t = tid; t < 768; t += 256) W2s[t] = W2[t];
    if (tid < 32) b1s[tid] = b1[tid];

    const int node = blockIdx.x * 8 + (tid >> 5);
    const int n = tid >> 5;
    const int l = tid & 31;
    const int f8 = l & 3;        // feature octet
    const int e8 = l >> 2;       // edge slot 0..7
    const bool valid = node < N;

    int beg = 0, cnt = 0;
    if (valid) { beg = rowptr[node]; cnt = rowptr[node + 1] - beg; }
    const int* ap = adj + beg;
    float a[8] = {0.f, 0.f, 0.f, 0.f, 0.f, 0.f, 0.f, 0.f};
    int j = 0;
    for (; j + 32 <= cnt; j += 32) {            // 32 edges/iter, 4 loads in flight
        int s0 = ap[j + e8];
        int s1 = ap[j + 8 + e8];
        int s2 = ap[j + 16 + e8];
        int s3 = ap[j + 24 + e8];
        uint2 v0 = hs1q[(size_t)s0 * 4 + f8];
        uint2 v1 = hs1q[(size_t)s1 * 4 + f8];
        uint2 v2 = hs1q[(size_t)s2 * 4 + f8];
        uint2 v3 = hs1q[(size_t)s3 * 4 + f8];
        acc8(v0, a); acc8(v1, a); acc8(v2, a); acc8(v3, a);
    }
    for (; j + 16 <= cnt; j += 16) {
        int s0 = ap[j + e8];
        int s1 = ap[j + 8 + e8];
        uint2 v0 = hs1q[(size_t)s0 * 4 + f8];
        uint2 v1 = hs1q[(size_t)s1 * 4 + f8];
        acc8(v0, a); acc8(v1, a);
    }
    for (; j + 8 <= cnt; j += 8) {
        int s0 = ap[j + e8];
        acc8(hs1q[(size_t)s0 * 4 + f8], a);
    }
    if (e8 < cnt - j) {                          // tail 0..7 edges
        int s0 = ap[j + e8];
        acc8(hs1q[(size_t)s0 * 4 + f8], a);
    }
#pragma unroll
    for (int k = 0; k < 8; k++) {                // fold 8 edge slots (lane bits 2,3,4)
        a[k] += __shfl_xor(a[k], 4);
        a[k] += __shfl_xor(a[k], 8);
        a[k] += __shfl_xor(a[k], 16);
    }

    __syncthreads();   // weight/bias staging visibility (all threads reach here)

    float di = 0.f;
    if (valid) {
        di = dinv[node];
        if (e8 == 0) {                           // lanes l<4 finalize 8 feats each
            float sv[8] = {0.f, 0.f, 0.f, 0.f, 0.f, 0.f, 0.f, 0.f};
            acc8(hs1q[(size_t)node * 4 + f8], sv);   // self-loop term
            const float c = di * IS1F;
#pragma unroll
            for (int k = 0; k < 8; k++)
                h1row[n][8 * f8 + k] = fmaxf(c * (a[k] + sv[k]) + b1s[8 * f8 + k], 0.f);
        }
    }
    // same-wave producer/consumer through LDS: no barrier needed
    if (valid) {
        float aa = 0.f;
        if (l < 24) {
#pragma unroll
            for (int k = 0; k < 32; k++) aa += h1row[n][k] * W2s[k * 24 + l];
        }
        hs2t[n][l] = (l < 24) ? aa * di * S2F : 0.f;
        if (l < 8)
            hs2out[(size_t)node * 8 + l] = enc4(hs2t[n][4 * l], hs2t[n][4 * l + 1],
                                                hs2t[n][4 * l + 2], hs2t[n][4 * l + 3]);
    }
}

// gather layer 2 (fp8 rows, 32 B, deep unroll) + fused finalize + node-MLP
__global__ __launch_bounds__(256) void gather2_kernel(
        const int* __restrict__ rowptr, const int* __restrict__ adj,
        const uint2* __restrict__ hs2q, const float* __restrict__ dinv,
        const float* __restrict__ b2,
        const float* __restrict__ Wn1, const float* __restrict__ bn1,
        const float* __restrict__ Wn2, const float* __restrict__ bn2,
        float* __restrict__ h2out, float* __restrict__ vout, int N) {
    __shared__ float Wn1s[24 * 16];
    __shared__ float b2s[32], bn1s[16], Wn2s[16];
    __shared__ float h2row[8][32];
    const int tid = threadIdx.x;
    for (int t = tid; t < 384; t += 256) Wn1s[t] = Wn1[t];
    if (tid < 32) b2s[tid] = (tid < 24) ? b2[tid] : 0.f;
    if (tid < 16) { bn1s[tid] = bn1[tid]; Wn2s[tid] = Wn2[tid]; }

    const int node = blockIdx.x * 8 + (tid >> 5);
    const int n = tid >> 5;
    const int l = tid & 31;
    const int f8 = l & 3;
    const int e8 = l >> 2;
    const bool valid = node < N;

    int beg = 0, cnt = 0;
    if (valid) { beg = rowptr[node]; cnt = rowptr[node + 1] - beg; }
    const int* ap = adj + beg;
    float a[8] = {0.f, 0.f, 0.f, 0.f, 0.f, 0.f, 0.f, 0.f};
    int j = 0;
    for (; j + 32 <= cnt; j += 32) {
        int s0 = ap[j + e8];
        int s1 = ap[j + 8 + e8];
        int s2 = ap[j + 16 + e8];
        int s3 = ap[j + 24 + e8];
        uint2 v0 = hs2q[(size_t)s0 * 4 + f8];
        uint2 v1 = hs2q[(size_t)s1 * 4 + f8];
        uint2 v2 = hs2q[(size_t)s2 * 4 + f8];
        uint2 v3 = hs2q[(size_t)s3 * 4 + f8];
        acc8(v0, a); acc8(v1, a); acc8(v2, a); acc8(v3, a);
    }
    for (; j + 16 <= cnt; j += 16) {
        int s0 = ap[j + e8];
        int s1 = ap[j + 8 + e8];
        uint2 v0 = hs2q[(size_t)s0 * 4 + f8];
        uint2 v1 = hs2q[(size_t)s1 * 4 + f8];
        acc8(v0, a); acc8(v1, a);
    }
    for (; j + 8 <= cnt; j += 8) {
        int s0 = ap[j + e8];
        acc8(hs2q[(size_t)s0 * 4 + f8], a);
    }
    if (e8 < cnt - j) {
        int s0 = ap[j + e8];
        acc8(hs2q[(size_t)s0 * 4 + f8], a);
    }
#pragma unroll
    for (int k = 0; k < 8; k++) {
        a[k] += __shfl_xor(a[k], 4);
        a[k] += __shfl_xor(a[k], 8);
        a[k] += __shfl_xor(a[k], 16);
    }

    __syncthreads();   // weight/bias staging visibility

    if (valid && e8 == 0) {
        float di = dinv[node];
        float sv[8] = {0.f, 0.f, 0.f, 0.f, 0.f, 0.f, 0.f, 0.f};
        acc8(hs2q[(size_t)node * 4 + f8], sv);
        const float c = di * IS2F;
#pragma unroll
        for (int k = 0; k < 8; k++)   // pad feats (>=24): staged 0, b2s 0 -> h2 0
            h2row[n][8 * f8 + k] = fmaxf(c * (a[k] + sv[k]) + b2s[8 * f8 + k], 0.f);
    }
    // same-wave producer/consumer through LDS
    if (valid && l < 24) h2out[(size_t)node * 24 + l] = h2row[n][l];

    float val = 0.f;
    if (valid && l < 16) {
        float u = bn1s[l];
#pragma unroll
        for (int k = 0; k < 24; k++) u += h2row[n][k] * Wn1s[k * 16 + l];
        val = fmaxf(u, 0.f) * Wn2s[l];
    }
    val += __shfl_down(val, 8, 16);
    val += __shfl_down(val, 4, 16);
    val += __shfl_down(val, 2, 16);
    val += __shfl_down(val, 1, 16);
    if (valid && l == 0) vout[node] = val + bn2[0];
}

// ---------------------------------------------------------------------------
// One block per graph (precomputed bounds): feature-parallel segment reduction,
// 4x-unrolled pass B, lane-parallel heads.
__global__ __launch_bounds__(256) void graph_kernel(
        const float* __restrict__ v, const float* __restrict__ h2,
        const int* __restrict__ starts,
        const float* __restrict__ Wg, const float* __restrict__ bg,
        const float* __restrict__ Wt, const float* __restrict__ bt,
        const float* __restrict__ Wb1p, const float* __restrict__ bb1p,
        const float* __restrict__ Wb2p, const float* __restrict__ bb2p,
        float* __restrict__ out_t, float* __restrict__ out_n,
        float* __restrict__ bbpre, int N) {
    const int g = blockIdx.x;
    const int tid = threadIdx.x;
    const int lane = tid & 63;
    const int wv = tid >> 6;

    const int start = starts[g];
    const int end = starts[g + 1];

    __shared__ float sm[4];
    __shared__ float pH[4][24], pW[4][24], pS[4];

    // pass A: max of v over the segment (grid-stride, wave reduce)
    float m = -INFINITY;
    for (int idx = start + tid; idx < end; idx += 256) m = fmaxf(m, v[idx]);
#pragma unroll
    for (int off = 32; off > 0; off >>= 1) m = fmaxf(m, __shfl_down(m, off, 64));
    if (lane == 0) sm[wv] = m;
    __syncthreads();
    m = fmaxf(fmaxf(sm[0], sm[1]), fmaxf(sm[2], sm[3]));

    // pass B: feature-parallel accumulation, 4x unrolled (4 node-rows in flight)
    const int half = lane >> 5;
    const int slot = wv * 2 + half;       // 0..7
    const int feat = lane & 31;
    const bool fa = feat < 24;
    float hs = 0.f, ws = 0.f, se = 0.f;
    int i = start + slot;
    for (; i + 24 < end; i += 32) {
        float v0 = v[i], v1 = v[i + 8], v2 = v[i + 16], v3 = v[i + 24];
        float h0 = 0.f, h1 = 0.f, hh2 = 0.f, h3 = 0.f;
        if (fa) {
            h0 = h2[(size_t)i * 24 + feat];
            h1 = h2[(size_t)(i + 8) * 24 + feat];
            hh2 = h2[(size_t)(i + 16) * 24 + feat];
            h3 = h2[(size_t)(i + 24) * 24 + feat];
        }
        float e0 = __expf(v0 - m), e1 = __expf(v1 - m);
        float e2 = __expf(v2 - m), e3 = __expf(v3 - m);
        if (feat == 0) se += (e0 + e1) + (e2 + e3);
        hs += (h0 + h1) + (hh2 + h3);
        ws += (e0 * h0 + e1 * h1) + (e2 * hh2 + e3 * h3);
    }
    for (; i < end; i += 8) {
        float vv = v[i];
        float e = __expf(vv - m);
        if (feat == 0) se += e;
        if (fa) {
            float hv = h2[(size_t)i * 24 + feat];
            hs += hv;
            ws += e * hv;
        }
    }
    // fold the two slots within this wave (lanes differ by 32)
    hs += __shfl_xor(hs, 32, 64);
    ws += __shfl_xor(ws, 32, 64);
    se += __shfl_xor(se, 32, 64);
    if (lane < 24) { pH[wv][lane] = hs; pW[wv][lane] = ws; }
    if (lane == 0) pS[wv] = se;
    __syncthreads();
    const float stot = pS[0] + pS[1] + pS[2] + pS[3];
    const float invs = (stot > 0.f) ? 1.f / stot : 0.f;

    // pass C: write normalized per-node softmax
    for (int idx = start + tid; idx < end; idx += 256)
        out_n[idx] = __expf(v[idx] - m) * invs;

    // heads: wave 0, lane-parallel
    const float denom = fmaxf((float)(end - start), 1.0f);
    if (tid < 32) {
        // t-head: gout[o] per lane, then width-32 shuffle reduce of gout.Wt
        float a = bg[tid];
#pragma unroll
        for (int k = 0; k < 24; k++) {
            float mean_k = (pH[0][k] + pH[1][k] + pH[2][k] + pH[3][k]) / denom;
            a += mean_k * Wg[k * 32 + tid];
        }
        float p0 = a * Wt[tid * 2];
        float p1 = a * Wt[tid * 2 + 1];
#pragma unroll
        for (int off = 16; off > 0; off >>= 1) {
            p0 += __shfl_down(p0, off, 32);
            p1 += __shfl_down(p1, off, 32);
        }
        if (tid == 0) {
            float t0 = p0 + bt[0], t1 = p1 + bt[1];
            float tm = fmaxf(t0, t1);
            float e0 = __expf(t0 - tm), e1 = __expf(t1 - tm);
            float ts = e0 + e1;
            out_t[g * 2 + 0] = e0 / ts;
            out_t[g * 2 + 1] = e1 / ts;
        }
    }
    if (tid < 16) {
        // b-head: u[j] per lane, then width-16 reduce for the 3 columns
        float u = bb1p[tid];
#pragma unroll
        for (int k = 0; k < 24; k++) {
            float bf_k = (pW[0][k] + pW[1][k] + pW[2][k] + pW[3][k]) * invs;
            u += bf_k * Wb1p[k * 16 + tid];
        }
        u = fmaxf(u, 0.f);
        float q0 = u * Wb2p[tid * 3 + 0];
        float q1 = u * Wb2p[tid * 3 + 1];
        float q2 = u * Wb2p[tid * 3 + 2];
#pragma unroll
        for (int off = 8; off > 0; off >>= 1) {
            q0 += __shfl_down(q0, off, 16);
            q1 += __shfl_down(q1, off, 16);
            q2 += __shfl_down(q2, off, 16);
        }
        if (tid == 0) {
            bbpre[g * 3 + 0] = q0 + bb2p[0];
            bbpre[g * 3 + 1] = q1 + bb2p[1];
            bbpre[g * 3 + 2] = q2 + bb2p[2];
        }
    }
}

// column softmax over the 256 graphs (axis=0), 3 columns
__global__ __launch_bounds__(256) void bb_kernel(
        const float* __restrict__ bbpre, float* __restrict__ out_bb) {
    __shared__ float red[NG];
    int g = threadIdx.x;
#pragma unroll
    for (int c = 0; c < 3; c++) {
        float vv = bbpre[g * 3 + c];
        red[g] = vv;
        __syncthreads();
        for (int off = 128; off > 0; off >>= 1) {
            if (g < off) red[g] = fmaxf(red[g], red[g + off]);
            __syncthreads();
        }
        float m = red[0];
        __syncthreads();
        float e = __expf(vv - m);
        red[g] = e;
        __syncthreads();
        for (int off = 128; off > 0; off >>= 1) {
            if (g < off) red[g] += red[g + off];
            __syncthreads();
        }
        float ssum = red[0];
        __syncthreads();
        out_bb[g * 3 + c] = e / ssum;
    }
}

extern "C" void kernel_launch(void* const* d_in, const int* in_sizes, int n_in,
                              void* d_out, int out_size, void* d_ws, size_t ws_size,
                              hipStream_t stream) {
    const float* x   = (const float*)d_in[0];
    const int*   ei  = (const int*)d_in[1];    // [2,E] flat: row=ei[0..E), col=ei[E..2E)
    const int*   bat = (const int*)d_in[2];
    const float* W1  = (const float*)d_in[3];
    const float* b1  = (const float*)d_in[4];
    const float* W2  = (const float*)d_in[5];
    const float* b2  = (const float*)d_in[6];
    const float* Wg  = (const float*)d_in[7];
    const float* bg  = (const float*)d_in[8];
    const float* Wt  = (const float*)d_in[9];
    const float* bt  = (const float*)d_in[10];
    const float* Wn1 = (const float*)d_in[11];
    const float* bn1 = (const float*)d_in[12];
    const float* Wn2 = (const float*)d_in[13];
    const float* bn2 = (const float*)d_in[14];
    const float* Wb1 = (const float*)d_in[15];
    const float* bb1 = (const float*)d_in[16];
    const float* Wb2 = (const float*)d_in[17];
    const float* bb2 = (const float*)d_in[18];

    const int N = in_sizes[2];
    const int E = in_sizes[1] / 2;
    const int NB = (N + 255) >> 8;       // buckets of 256 nodes
    const int M = NB * NBLK;             // blockOff matrix size

    // workspace layout (4B units):
    // persistent: rowptr[N+1] | dinv[N] | adj[E] | bucketBase[NB+1] | bucketTot[NB] | starts[NG+1]
    // transient (aliased union):
    //   build:   blockOff[M] | pairs[E]
    //   compute: hs1 fp8 (2N) -> h2 f32 (24N) + v (N) ; hs2 fp8 at +26N (2N) ; bbpre at +28N
    auto rnd4 = [](size_t v) { return (v + 3) & ~(size_t)3; };
    size_t oRow = 0;
    size_t oDin = oRow + rnd4((size_t)N + 1);
    size_t oAdj = oDin + rnd4((size_t)N);
    size_t oBB  = oAdj + rnd4((size_t)E);
    size_t oTot = oBB + rnd4((size_t)NB + 1);
    size_t oSt  = oTot + rnd4((size_t)NB);
    size_t oT   = oSt + rnd4((size_t)NG + 1);
    size_t oPar = oT + rnd4((size_t)M);

    int*   wsi     = (int*)d_ws;
    float* wsf     = (float*)d_ws;
    int*   rowptr  = wsi + oRow;
    float* dinv    = wsf + oDin;
    int*   adj     = wsi + oAdj;
    int*   bbase   = wsi + oBB;
    int*   btot    = wsi + oTot;
    int*   starts  = wsi + oSt;
    int*   blkoff  = wsi + oT;
    int*   pairs   = wsi + oPar;
    unsigned* hs1b = (unsigned*)(wsf + oT);                  // 2N units
    float* h2      = wsf + oT;                               // reuses hs1b region after gather1
    float* vbuf    = wsf + oT + (size_t)24 * N;
    unsigned* hs2b = (unsigned*)(wsf + oT + (size_t)26 * N); // 2N units
    float* bbpre   = wsf + oT + (size_t)28 * N;

    float* out_t  = (float*)d_out;          // [256,2]
    float* out_n  = out_t + 2 * NG;         // [N,1]
    float* out_bb = out_t + 2 * NG + N;     // [256,3]

    const int B = 256;

    // CSR build + segment bounds
    (void)hipMemsetAsync(btot, 0, (size_t)NB * sizeof(int), stream);
    bounds_kernel<<<(N + B - 1) / B, B, 0, stream>>>(bat, starts, N);
    hist_bucket_kernel<<<NBLK, B, 0, stream>>>(ei + E, blkoff, btot, E, NB);
    tiny_scan_kernel<<<1, 512, 0, stream>>>(btot, bbase, NB);
    scatter_pairs_kernel<<<NBLK, B, 0, stream>>>(ei, blkoff, bbase, pairs, E, NB);
    csr_bucket_kernel<<<NB, B, 0, stream>>>(pairs, bbase, rowptr, adj, dinv, N, E);

    // GCN + heads (fp8 staging rows, fp32 accumulation, 4-deep gather unroll)
    hs1_kernel<<<(N + 7) / 8, B, 0, stream>>>(x, W1, dinv, hs1b, N);
    gather1_kernel<<<(N + 7) / 8, B, 0, stream>>>(rowptr, adj, (const uint2*)hs1b,
                                                  dinv, b1, W2, hs2b, N);
    gather2_kernel<<<(N + 7) / 8, B, 0, stream>>>(rowptr, adj, (const uint2*)hs2b,
                                                  dinv, b2, Wn1, bn1, Wn2, bn2, h2, vbuf, N);
    graph_kernel<<<NG, B, 0, stream>>>(vbuf, h2, starts, Wg, bg, Wt, bt,
                                       Wb1, bb1, Wb2, bb2, out_t, out_n, bbpre, N);
    bb_kernel<<<1, B, 0, stream>>>(bbpre, out_bb);
}

// Round 16
// 296.052 us; speedup vs baseline: 1.1115x; 1.0039x over previous
//
#include <hip/hip_runtime.h>
#include <math.h>

#define NG 256     // NUM_GRAPHS
#define NBLK 256   // blocks in histogram / pair-scatter passes
// bucket = target >> 8 (256 nodes/bucket, NB<=512); src packs in 17 bits (N <= 131072)

// fp8-e4m3 staging scales (powers of 2: exactly invertible)
#define S1F 16.0f
#define IS1F 0.0625f
#define S2F 64.0f
#define IS2F 0.015625f

typedef __attribute__((ext_vector_type(2))) float f32x2;

__device__ __forceinline__ unsigned enc4(float f0, float f1, float f2, float f3) {
    int r = __builtin_amdgcn_cvt_pk_fp8_f32(f0, f1, 0, false);
    r = __builtin_amdgcn_cvt_pk_fp8_f32(f2, f3, r, true);
    return (unsigned)r;
}
// accumulate 8 fp8 feats (one uint2) into 4 packed f32x2 accumulators
// a[k] covers feats {2k, 2k+1} of the octet -> v_pk_add_f32
__device__ __forceinline__ void acc8p(uint2 v, f32x2 (&a)[4]) {
    a[0] += __builtin_amdgcn_cvt_pk_f32_fp8((int)v.x, false);
    a[1] += __builtin_amdgcn_cvt_pk_f32_fp8((int)v.x, true);
    a[2] += __builtin_amdgcn_cvt_pk_f32_fp8((int)v.y, false);
    a[3] += __builtin_amdgcn_cvt_pk_f32_fp8((int)v.y, true);
}

// ---------------------------------------------------------------------------
// K1: per-block histogram of edge targets into NB buckets (LDS atomics), then
// reserve this block's range in each bucket via one global atomic per bucket.
__global__ __launch_bounds__(256) void hist_bucket_kernel(
        const int* __restrict__ col, int* __restrict__ blockOff,
        int* __restrict__ bucketTot, int E, int NB) {
    __shared__ int h[512];
    h[threadIdx.x] = 0; h[threadIdx.x + 256] = 0;
    __syncthreads();
    const int chunk = (((E + NBLK - 1) / NBLK) + 3) & ~3;   // 4-aligned per-block chunk
    const int beg = blockIdx.x * chunk;
    const int end = min(beg + chunk, E);
    if ((E & 3) == 0) {
        int e = beg + threadIdx.x * 4;
        for (; e + 3 < end; e += 1024) {
            int4 c = *(const int4*)(col + e);
            atomicAdd(&h[c.x >> 8], 1);
            atomicAdd(&h[c.y >> 8], 1);
            atomicAdd(&h[c.z >> 8], 1);
            atomicAdd(&h[c.w >> 8], 1);
        }
        for (; e < end; e++) atomicAdd(&h[col[e] >> 8], 1);
    } else {
        for (int e = beg + threadIdx.x; e < end; e += 256)
            atomicAdd(&h[col[e] >> 8], 1);
    }
    __syncthreads();
    for (int t = threadIdx.x; t < NB; t += 256) {
        int off = atomicAdd(&bucketTot[t], h[t]);   // reserve range (order arbitrary)
        blockOff[t * NBLK + blockIdx.x] = off;
    }
}

// K2: tiny exclusive scan over bucketTot[NB] -> bucketBase[NB+1]  (NB <= 512)
__global__ __launch_bounds__(512) void tiny_scan_kernel(
        const int* __restrict__ bucketTot, int* __restrict__ bucketBase, int NB) {
    __shared__ int part[512];
    const int t = threadIdx.x;
    int v = (t < NB) ? bucketTot[t] : 0;
    part[t] = v;
    __syncthreads();
    for (int o = 1; o < 512; o <<= 1) {
        int u = (t >= o) ? part[t - o] : 0;
        __syncthreads();
        part[t] += u;
        __syncthreads();
    }
    if (t < NB) bucketBase[t] = part[t] - v;   // exclusive
    if (t == NB) bucketBase[NB] = part[NB - 1];
    if (t == 511 && NB == 512) bucketBase[NB] = part[511];
}

// K3: scatter packed (local_tgt<<17 | src) pairs, grouped by bucket (LDS cursors)
__global__ __launch_bounds__(256) void scatter_pairs_kernel(
        const int* __restrict__ ei, const int* __restrict__ blockOff,
        const int* __restrict__ bucketBase, int* __restrict__ pairs, int E, int NB) {
    __shared__ int cur[512];
    for (int t = threadIdx.x; t < NB; t += 256)
        cur[t] = bucketBase[t] + blockOff[t * NBLK + blockIdx.x];
    __syncthreads();
    const int chunk = (((E + NBLK - 1) / NBLK) + 3) & ~3;
    const int beg = blockIdx.x * chunk;
    const int end = min(beg + chunk, E);
    if ((E & 3) == 0) {
        int e = beg + threadIdx.x * 4;
        for (; e + 3 < end; e += 1024) {
            int4 s = *(const int4*)(ei + e);
            int4 tg = *(const int4*)(ei + E + e);
            int p0 = atomicAdd(&cur[tg.x >> 8], 1);
            pairs[p0] = (int)(((unsigned)(tg.x & 255) << 17) | (unsigned)s.x);
            int p1 = atomicAdd(&cur[tg.y >> 8], 1);
            pairs[p1] = (int)(((unsigned)(tg.y & 255) << 17) | (unsigned)s.y);
            int p2 = atomicAdd(&cur[tg.z >> 8], 1);
            pairs[p2] = (int)(((unsigned)(tg.z & 255) << 17) | (unsigned)s.z);
            int p3 = atomicAdd(&cur[tg.w >> 8], 1);
            pairs[p3] = (int)(((unsigned)(tg.w & 255) << 17) | (unsigned)s.w);
        }
        for (; e < end; e++) {
            int src = ei[e];
            int tgt = ei[E + e];
            int pos = atomicAdd(&cur[tgt >> 8], 1);
            pairs[pos] = (int)(((unsigned)(tgt & 255) << 17) | (unsigned)src);
        }
    } else {
        for (int e = beg + threadIdx.x; e < end; e += 256) {
            int src = ei[e];
            int tgt = ei[E + e];
            int pos = atomicAdd(&cur[tgt >> 8], 1);
            pairs[pos] = (int)(((unsigned)(tgt & 255) << 17) | (unsigned)src);
        }
    }
}

// K4: one block per bucket (256 nodes): LDS hist + scan -> rowptr, dinv, adj
__global__ __launch_bounds__(256) void csr_bucket_kernel(
        const int* __restrict__ pairs, const int* __restrict__ bucketBase,
        int* __restrict__ rowptr, int* __restrict__ adj,
        float* __restrict__ dinv, int N, int E) {
    __shared__ int h[256];
    __shared__ int sc[256];
    __shared__ int cur[256];
    const int b = blockIdx.x, t = threadIdx.x;
    const int base = bucketBase[b];
    const int end = bucketBase[b + 1];
    h[t] = 0;
    __syncthreads();
    for (int i = base + t; i < end; i += 256)
        atomicAdd(&h[(unsigned)pairs[i] >> 17], 1);
    __syncthreads();
    const int v = h[t];
    sc[t] = v;
    __syncthreads();
    for (int o = 1; o < 256; o <<= 1) {
        int u = (t >= o) ? sc[t - o] : 0;
        __syncthreads();
        sc[t] += u;
        __syncthreads();
    }
    const int ex = sc[t] - v;
    const int node = (b << 8) + t;
    if (node < N) {
        rowptr[node] = base + ex;
        dinv[node] = rsqrtf((float)v + 1.0f);
    }
    cur[t] = base + ex;
    __syncthreads();
    for (int i = base + t; i < end; i += 256) {
        unsigned p = (unsigned)pairs[i];
        int pos = atomicAdd(&cur[p >> 17], 1);
        adj[pos] = (int)(p & 0x1FFFFu);
    }
    if (b == 0 && t == 0) rowptr[N] = E;
}

// K5: segment bounds from sorted batch: starts[g] = lower_bound(batch, g), starts[NG]=N
__global__ __launch_bounds__(256) void bounds_kernel(
        const int* __restrict__ batch, int* __restrict__ starts, int N) {
    int i = blockIdx.x * blockDim.x + threadIdx.x;
    if (i >= N) return;
    int b = batch[i];
    int bp = (i == 0) ? -1 : batch[i - 1];
    for (int g = bp + 1; g <= b; g++) starts[g] = i;
    if (i == N - 1)
        for (int g = b + 1; g <= NG; g++) starts[g] = N;
}

// ---------------------------------------------------------------------------
// hs1[i][f] = fp8( (x[i]@W1)[f] * dinv[i] * S1 )   (32 feats -> 32 B rows)
__global__ __launch_bounds__(256) void hs1_kernel(
        const float* __restrict__ x, const float* __restrict__ W,
        const float* __restrict__ dinv, unsigned* __restrict__ hs, int N) {
    __shared__ float Ws[32 * 32];
    __shared__ float tmp[8][32];
    for (int t = threadIdx.x; t < 1024; t += blockDim.x) Ws[t] = W[t];
    __syncthreads();
    const int tid = threadIdx.x;
    const int node = blockIdx.x * 8 + (tid >> 5);
    const int n = tid >> 5, f = tid & 31;
    if (node < N) {
        const float* xr = x + (size_t)node * 32;
        float acc = 0.f;
#pragma unroll
        for (int k = 0; k < 32; k++) acc += xr[k] * Ws[k * 32 + f];
        tmp[n][f] = acc * dinv[node] * S1F;
        if (f < 8)   // same-wave producer/consumer
            hs[(size_t)node * 8 + f] = enc4(tmp[n][4 * f], tmp[n][4 * f + 1],
                                            tmp[n][4 * f + 2], tmp[n][4 * f + 3]);
    }
}

// gather layer 1 (fp8 rows, 32 B: 4 lanes/row, 8 edge slots, 32 edges/iter
// with 4 independent row loads in flight; packed f32x2 accumulation)
__global__ __launch_bounds__(256) void gather1_kernel(
        const int* __restrict__ rowptr, const int* __restrict__ adj,
        const uint2* __restrict__ hs1q, const float* __restrict__ dinv,
        const float* __restrict__ b1, const float* __restrict__ W2,
        unsigned* __restrict__ hs2out, int N) {
    __shared__ float W2s[32 * 24];
    __shared__ float b1s[32];
    __shared__ float h1row[8][32];
    __shared__ float hs2t[8][32];
    const int tid = threadIdx.x;
    for (int t = tid; t < 768; t += 256) W2s[t] = W2[t];
    if (tid < 32) b1s[tid] = b1[tid];

    const int node = blockIdx.x * 8 + (tid >> 5);
    const int n = tid >> 5;
    const int l = tid & 31;
    const int f8 = l & 3;        // feature octet
    const int e8 = l >> 2;       // edge slot 0..7
    const bool valid = node < N;

    int beg = 0, cnt = 0;
    if (valid) { beg = rowptr[node]; cnt = rowptr[node + 1] - beg; }
    const int* ap = adj + beg;
    f32x2 a[4];
#pragma unroll
    for (int k = 0; k < 4; k++) { a[k][0] = 0.f; a[k][1] = 0.f; }
    int j = 0;
    for (; j + 32 <= cnt; j += 32) {            // 32 edges/iter, 4 loads in flight
        int s0 = ap[j + e8];
        int s1 = ap[j + 8 + e8];
        int s2 = ap[j + 16 + e8];
        int s3 = ap[j + 24 + e8];
        uint2 v0 = hs1q[(size_t)s0 * 4 + f8];
        uint2 v1 = hs1q[(size_t)s1 * 4 + f8];
        uint2 v2 = hs1q[(size_t)s2 * 4 + f8];
        uint2 v3 = hs1q[(size_t)s3 * 4 + f8];
        acc8p(v0, a); acc8p(v1, a); acc8p(v2, a); acc8p(v3, a);
    }
    for (; j + 16 <= cnt; j += 16) {
        int s0 = ap[j + e8];
        int s1 = ap[j + 8 + e8];
        uint2 v0 = hs1q[(size_t)s0 * 4 + f8];
        uint2 v1 = hs1q[(size_t)s1 * 4 + f8];
        acc8p(v0, a); acc8p(v1, a);
    }
    for (; j + 8 <= cnt; j += 8) {
        int s0 = ap[j + e8];
        acc8p(hs1q[(size_t)s0 * 4 + f8], a);
    }
    if (e8 < cnt - j) {                          // tail 0..7 edges
        int s0 = ap[j + e8];
        acc8p(hs1q[(size_t)s0 * 4 + f8], a);
    }
#pragma unroll
    for (int k = 0; k < 4; k++) {                // fold 8 edge slots (lane bits 2,3,4)
        float x0 = a[k][0], x1 = a[k][1];
        x0 += __shfl_xor(x0, 4); x0 += __shfl_xor(x0, 8); x0 += __shfl_xor(x0, 16);
        x1 += __shfl_xor(x1, 4); x1 += __shfl_xor(x1, 8); x1 += __shfl_xor(x1, 16);
        a[k][0] = x0; a[k][1] = x1;
    }

    __syncthreads();   // weight/bias staging visibility (all threads reach here)

    float di = 0.f;
    if (valid) {
        di = dinv[node];
        if (e8 == 0) {                           // lanes l<4 finalize 8 feats each
            f32x2 s[4];
#pragma unroll
            for (int k = 0; k < 4; k++) { s[k][0] = 0.f; s[k][1] = 0.f; }
            acc8p(hs1q[(size_t)node * 4 + f8], s);   // self-loop term
            const float c = di * IS1F;
#pragma unroll
            for (int k = 0; k < 4; k++) {
                h1row[n][8 * f8 + 2 * k]     = fmaxf(c * (a[k][0] + s[k][0]) + b1s[8 * f8 + 2 * k], 0.f);
                h1row[n][8 * f8 + 2 * k + 1] = fmaxf(c * (a[k][1] + s[k][1]) + b1s[8 * f8 + 2 * k + 1], 0.f);
            }
        }
    }
    // same-wave producer/consumer through LDS: no barrier needed
    if (valid) {
        float aa = 0.f;
        if (l < 24) {
#pragma unroll
            for (int k = 0; k < 32; k++) aa += h1row[n][k] * W2s[k * 24 + l];
        }
        hs2t[n][l] = (l < 24) ? aa * di * S2F : 0.f;
        if (l < 8)
            hs2out[(size_t)node * 8 + l] = enc4(hs2t[n][4 * l], hs2t[n][4 * l + 1],
                                                hs2t[n][4 * l + 2], hs2t[n][4 * l + 3]);
    }
}

// gather layer 2 (fp8 rows, 32 B, deep unroll, packed f32x2 accumulation)
//   + fused finalize + node-MLP
__global__ __launch_bounds__(256) void gather2_kernel(
        const int* __restrict__ rowptr, const int* __restrict__ adj,
        const uint2* __restrict__ hs2q, const float* __restrict__ dinv,
        const float* __restrict__ b2,
        const float* __restrict__ Wn1, const float* __restrict__ bn1,
        const float* __restrict__ Wn2, const float* __restrict__ bn2,
        float* __restrict__ h2out, float* __restrict__ vout, int N) {
    __shared__ float Wn1s[24 * 16];
    __shared__ float b2s[32], bn1s[16], Wn2s[16];
    __shared__ float h2row[8][32];
    const int tid = threadIdx.x;
    for (int t = tid; t < 384; t += 256) Wn1s[t] = Wn1[t];
    if (tid < 32) b2s[tid] = (tid < 24) ? b2[tid] : 0.f;
    if (tid < 16) { bn1s[tid] = bn1[tid]; Wn2s[tid] = Wn2[tid]; }

    const int node = blockIdx.x * 8 + (tid >> 5);
    const int n = tid >> 5;
    const int l = tid & 31;
    const int f8 = l & 3;
    const int e8 = l >> 2;
    const bool valid = node < N;

    int beg = 0, cnt = 0;
    if (valid) { beg = rowptr[node]; cnt = rowptr[node + 1] - beg; }
    const int* ap = adj + beg;
    f32x2 a[4];
#pragma unroll
    for (int k = 0; k < 4; k++) { a[k][0] = 0.f; a[k][1] = 0.f; }
    int j = 0;
    for (; j + 32 <= cnt; j += 32) {
        int s0 = ap[j + e8];
        int s1 = ap[j + 8 + e8];
        int s2 = ap[j + 16 + e8];
        int s3 = ap[j + 24 + e8];
        uint2 v0 = hs2q[(size_t)s0 * 4 + f8];
        uint2 v1 = hs2q[(size_t)s1 * 4 + f8];
        uint2 v2 = hs2q[(size_t)s2 * 4 + f8];
        uint2 v3 = hs2q[(size_t)s3 * 4 + f8];
        acc8p(v0, a); acc8p(v1, a); acc8p(v2, a); acc8p(v3, a);
    }
    for (; j + 16 <= cnt; j += 16) {
        int s0 = ap[j + e8];
        int s1 = ap[j + 8 + e8];
        uint2 v0 = hs2q[(size_t)s0 * 4 + f8];
        uint2 v1 = hs2q[(size_t)s1 * 4 + f8];
        acc8p(v0, a); acc8p(v1, a);
    }
    for (; j + 8 <= cnt; j += 8) {
        int s0 = ap[j + e8];
        acc8p(hs2q[(size_t)s0 * 4 + f8], a);
    }
    if (e8 < cnt - j) {
        int s0 = ap[j + e8];
        acc8p(hs2q[(size_t)s0 * 4 + f8], a);
    }
#pragma unroll
    for (int k = 0; k < 4; k++) {
        float x0 = a[k][0], x1 = a[k][1];
        x0 += __shfl_xor(x0, 4); x0 += __shfl_xor(x0, 8); x0 += __shfl_xor(x0, 16);
        x1 += __shfl_xor(x1, 4); x1 += __shfl_xor(x1, 8); x1 += __shfl_xor(x1, 16);
        a[k][0] = x0; a[k][1] = x1;
    }

    __syncthreads();   // weight/bias staging visibility

    if (valid && e8 == 0) {
        float di = dinv[node];
        f32x2 s[4];
#pragma unroll
        for (int k = 0; k < 4; k++) { s[k][0] = 0.f; s[k][1] = 0.f; }
        acc8p(hs2q[(size_t)node * 4 + f8], s);
        const float c = di * IS2F;
#pragma unroll
        for (int k = 0; k < 4; k++) {   // pad feats (>=24): staged 0, b2s 0 -> h2 0
            h2row[n][8 * f8 + 2 * k]     = fmaxf(c * (a[k][0] + s[k][0]) + b2s[8 * f8 + 2 * k], 0.f);
            h2row[n][8 * f8 + 2 * k + 1] = fmaxf(c * (a[k][1] + s[k][1]) + b2s[8 * f8 + 2 * k + 1], 0.f);
        }
    }
    // same-wave producer/consumer through LDS
    if (valid && l < 24) h2out[(size_t)node * 24 + l] = h2row[n][l];

    float val = 0.f;
    if (valid && l < 16) {
        float u = bn1s[l];
#pragma unroll
        for (int k = 0; k < 24; k++) u += h2row[n][k] * Wn1s[k * 16 + l];
        val = fmaxf(u, 0.f) * Wn2s[l];
    }
    val += __shfl_down(val, 8, 16);
    val += __shfl_down(val, 4, 16);
    val += __shfl_down(val, 2, 16);
    val += __shfl_down(val, 1, 16);
    if (valid && l == 0) vout[node] = val + bn2[0];
}

// ---------------------------------------------------------------------------
// One block per graph (precomputed bounds): feature-parallel segment reduction,
// 4x-unrolled pass B, lane-parallel heads.
__global__ __launch_bounds__(256) void graph_kernel(
        const float* __restrict__ v, const float* __restrict__ h2,
        const int* __restrict__ starts,
        const float* __restrict__ Wg, const float* __restrict__ bg,
        const float* __restrict__ Wt, const float* __restrict__ bt,
        const float* __restrict__ Wb1p, const float* __restrict__ bb1p,
        const float* __restrict__ Wb2p, const float* __restrict__ bb2p,
        float* __restrict__ out_t, float* __restrict__ out_n,
        float* __restrict__ bbpre, int N) {
    const int g = blockIdx.x;
    const int tid = threadIdx.x;
    const int lane = tid & 63;
    const int wv = tid >> 6;

    const int start = starts[g];
    const int end = starts[g + 1];

    __shared__ float sm[4];
    __shared__ float pH[4][24], pW[4][24], pS[4];

    // pass A: max of v over the segment (grid-stride, wave reduce)
    float m = -INFINITY;
    for (int idx = start + tid; idx < end; idx += 256) m = fmaxf(m, v[idx]);
#pragma unroll
    for (int off = 32; off > 0; off >>= 1) m = fmaxf(m, __shfl_down(m, off, 64));
    if (lane == 0) sm[wv] = m;
    __syncthreads();
    m = fmaxf(fmaxf(sm[0], sm[1]), fmaxf(sm[2], sm[3]));

    // pass B: feature-parallel accumulation, 4x unrolled (4 node-rows in flight)
    const int half = lane >> 5;
    const int slot = wv * 2 + half;       // 0..7
    const int feat = lane & 31;
    const bool fa = feat < 24;
    float hs = 0.f, ws = 0.f, se = 0.f;
    int i = start + slot;
    for (; i + 24 < end; i += 32) {
        float v0 = v[i], v1 = v[i + 8], v2 = v[i + 16], v3 = v[i + 24];
        float h0 = 0.f, h1 = 0.f, hh2 = 0.f, h3 = 0.f;
        if (fa) {
            h0 = h2[(size_t)i * 24 + feat];
            h1 = h2[(size_t)(i + 8) * 24 + feat];
            hh2 = h2[(size_t)(i + 16) * 24 + feat];
            h3 = h2[(size_t)(i + 24) * 24 + feat];
        }
        float e0 = __expf(v0 - m), e1 = __expf(v1 - m);
        float e2 = __expf(v2 - m), e3 = __expf(v3 - m);
        if (feat == 0) se += (e0 + e1) + (e2 + e3);
        hs += (h0 + h1) + (hh2 + h3);
        ws += (e0 * h0 + e1 * h1) + (e2 * hh2 + e3 * h3);
    }
    for (; i < end; i += 8) {
        float vv = v[i];
        float e = __expf(vv - m);
        if (feat == 0) se += e;
        if (fa) {
            float hv = h2[(size_t)i * 24 + feat];
            hs += hv;
            ws += e * hv;
        }
    }
    // fold the two slots within this wave (lanes differ by 32)
    hs += __shfl_xor(hs, 32, 64);
    ws += __shfl_xor(ws, 32, 64);
    se += __shfl_xor(se, 32, 64);
    if (lane < 24) { pH[wv][lane] = hs; pW[wv][lane] = ws; }
    if (lane == 0) pS[wv] = se;
    __syncthreads();
    const float stot = pS[0] + pS[1] + pS[2] + pS[3];
    const float invs = (stot > 0.f) ? 1.f / stot : 0.f;

    // pass C: write normalized per-node softmax
    for (int idx = start + tid; idx < end; idx += 256)
        out_n[idx] = __expf(v[idx] - m) * invs;

    // heads: wave 0, lane-parallel
    const float denom = fmaxf((float)(end - start), 1.0f);
    if (tid < 32) {
        // t-head: gout[o] per lane, then width-32 shuffle reduce of gout.Wt
        float a = bg[tid];
#pragma unroll
        for (int k = 0; k < 24; k++) {
            float mean_k = (pH[0][k] + pH[1][k] + pH[2][k] + pH[3][k]) / denom;
            a += mean_k * Wg[k * 32 + tid];
        }
        float p0 = a * Wt[tid * 2];
        float p1 = a * Wt[tid * 2 + 1];
#pragma unroll
        for (int off = 16; off > 0; off >>= 1) {
            p0 += __shfl_down(p0, off, 32);
            p1 += __shfl_down(p1, off, 32);
        }
        if (tid == 0) {
            float t0 = p0 + bt[0], t1 = p1 + bt[1];
            float tm = fmaxf(t0, t1);
            float e0 = __expf(t0 - tm), e1 = __expf(t1 - tm);
            float ts = e0 + e1;
            out_t[g * 2 + 0] = e0 / ts;
            out_t[g * 2 + 1] = e1 / ts;
        }
    }
    if (tid < 16) {
        // b-head: u[j] per lane, then width-16 reduce for the 3 columns
        float u = bb1p[tid];
#pragma unroll
        for (int k = 0; k < 24; k++) {
            float bf_k = (pW[0][k] + pW[1][k] + pW[2][k] + pW[3][k]) * invs;
            u += bf_k * Wb1p[k * 16 + tid];
        }
        u = fmaxf(u, 0.f);
        float q0 = u * Wb2p[tid * 3 + 0];
        float q1 = u * Wb2p[tid * 3 + 1];
        float q2 = u * Wb2p[tid * 3 + 2];
#pragma unroll
        for (int off = 8; off > 0; off >>= 1) {
            q0 += __shfl_down(q0, off, 16);
            q1 += __shfl_down(q1, off, 16);
            q2 += __shfl_down(q2, off, 16);
        }
        if (tid == 0) {
            bbpre[g * 3 + 0] = q0 + bb2p[0];
            bbpre[g * 3 + 1] = q1 + bb2p[1];
            bbpre[g * 3 + 2] = q2 + bb2p[2];
        }
    }
}

// column softmax over the 256 graphs (axis=0), 3 columns
__global__ __launch_bounds__(256) void bb_kernel(
        const float* __restrict__ bbpre, float* __restrict__ out_bb) {
    __shared__ float red[NG];
    int g = threadIdx.x;
#pragma unroll
    for (int c = 0; c < 3; c++) {
        float vv = bbpre[g * 3 + c];
        red[g] = vv;
        __syncthreads();
        for (int off = 128; off > 0; off >>= 1) {
            if (g < off) red[g] = fmaxf(red[g], red[g + off]);
            __syncthreads();
        }
        float m = red[0];
        __syncthreads();
        float e = __expf(vv - m);
        red[g] = e;
        __syncthreads();
        for (int off = 128; off > 0; off >>= 1) {
            if (g < off) red[g] += red[g + off];
            __syncthreads();
        }
        float ssum = red[0];
        __syncthreads();
        out_bb[g * 3 + c] = e / ssum;
    }
}

extern "C" void kernel_launch(void* const* d_in, const int* in_sizes, int n_in,
                              void* d_out, int out_size, void* d_ws, size_t ws_size,
                              hipStream_t stream) {
    const float* x   = (const float*)d_in[0];
    const int*   ei  = (const int*)d_in[1];    // [2,E] flat: row=ei[0..E), col=ei[E..2E)
    const int*   bat = (const int*)d_in[2];
    const float* W1  = (const float*)d_in[3];
    const float* b1  = (const float*)d_in[4];
    const float* W2  = (const float*)d_in[5];
    const float* b2  = (const float*)d_in[6];
    const float* Wg  = (const float*)d_in[7];
    const float* bg  = (const float*)d_in[8];
    const float* Wt  = (const float*)d_in[9];
    const float* bt  = (const float*)d_in[10];
    const float* Wn1 = (const float*)d_in[11];
    const float* bn1 = (const float*)d_in[12];
    const float* Wn2 = (const float*)d_in[13];
    const float* bn2 = (const float*)d_in[14];
    const float* Wb1 = (const float*)d_in[15];
    const float* bb1 = (const float*)d_in[16];
    const float* Wb2 = (const float*)d_in[17];
    const float* bb2 = (const float*)d_in[18];

    const int N = in_sizes[2];
    const int E = in_sizes[1] / 2;
    const int NB = (N + 255) >> 8;       // buckets of 256 nodes
    const int M = NB * NBLK;             // blockOff matrix size

    // workspace layout (4B units):
    // persistent: rowptr[N+1] | dinv[N] | adj[E] | bucketBase[NB+1] | bucketTot[NB] | starts[NG+1]
    // transient (aliased union):
    //   build:   blockOff[M] | pairs[E]
    //   compute: hs1 fp8 (2N) -> h2 f32 (24N) + v (N) ; hs2 fp8 at +26N (2N) ; bbpre at +28N
    auto rnd4 = [](size_t v) { return (v + 3) & ~(size_t)3; };
    size_t oRow = 0;
    size_t oDin = oRow + rnd4((size_t)N + 1);
    size_t oAdj = oDin + rnd4((size_t)N);
    size_t oBB  = oAdj + rnd4((size_t)E);
    size_t oTot = oBB + rnd4((size_t)NB + 1);
    size_t oSt  = oTot + rnd4((size_t)NB);
    size_t oT   = oSt + rnd4((size_t)NG + 1);
    size_t oPar = oT + rnd4((size_t)M);

    int*   wsi     = (int*)d_ws;
    float* wsf     = (float*)d_ws;
    int*   rowptr  = wsi + oRow;
    float* dinv    = wsf + oDin;
    int*   adj     = wsi + oAdj;
    int*   bbase   = wsi + oBB;
    int*   btot    = wsi + oTot;
    int*   starts  = wsi + oSt;
    int*   blkoff  = wsi + oT;
    int*   pairs   = wsi + oPar;
    unsigned* hs1b = (unsigned*)(wsf + oT);                  // 2N units
    float* h2      = wsf + oT;                               // reuses hs1b region after gather1
    float* vbuf    = wsf + oT + (size_t)24 * N;
    unsigned* hs2b = (unsigned*)(wsf + oT + (size_t)26 * N); // 2N units
    float* bbpre   = wsf + oT + (size_t)28 * N;

    float* out_t  = (float*)d_out;          // [256,2]
    float* out_n  = out_t + 2 * NG;         // [N,1]
    float* out_bb = out_t + 2 * NG + N;     // [256,3]

    const int B = 256;

    // CSR build + segment bounds
    (void)hipMemsetAsync(btot, 0, (size_t)NB * sizeof(int), stream);
    bounds_kernel<<<(N + B - 1) / B, B, 0, stream>>>(bat, starts, N);
    hist_bucket_kernel<<<NBLK, B, 0, stream>>>(ei + E, blkoff, btot, E, NB);
    tiny_scan_kernel<<<1, 512, 0, stream>>>(btot, bbase, NB);
    scatter_pairs_kernel<<<NBLK, B, 0, stream>>>(ei, blkoff, bbase, pairs, E, NB);
    csr_bucket_kernel<<<NB, B, 0, stream>>>(pairs, bbase, rowptr, adj, dinv, N, E);

    // GCN + heads (fp8 staging rows, packed f32x2 accumulation, 4-deep unroll)
    hs1_kernel<<<(N + 7) / 8, B, 0, stream>>>(x, W1, dinv, hs1b, N);
    gather1_kernel<<<(N + 7) / 8, B, 0, stream>>>(rowptr, adj, (const uint2*)hs1b,
                                                  dinv, b1, W2, hs2b, N);
    gather2_kernel<<<(N + 7) / 8, B, 0, stream>>>(rowptr, adj, (const uint2*)hs2b,
                                                  dinv, b2, Wn1, bn1, Wn2, bn2, h2, vbuf, N);
    graph_kernel<<<NG, B, 0, stream>>>(vbuf, h2, starts, Wg, bg, Wt, bt,
                                       Wb1, bb1, Wb2, bb2, out_t, out_n, bbpre, N);
    bb_kernel<<<1, B, 0, stream>>>(bbpre, out_bb);
}